// Round 1
// baseline (390.431 us; speedup 1.0000x reference)
//
#include <hip/hip_runtime.h>
#include <hip/hip_bf16.h>
#include <stdint.h>
#include <stddef.h>

// ---------------------------------------------------------------------------
// RingAttentionLayer on MI355X (gfx950)
// Pipeline: fp32->bf16 convert, fused QKV GEMM (bf16 MFMA), dual-accumulator
// flash attention (masked + unmasked stats in one pass), O-proj GEMM.
// All MFMA: v_mfma_f32_16x16x32_bf16. LDS staging via global_load_lds(16B)
// with XOR-swizzled layouts (swizzle applied on global address per-lane since
// LDS dest of global_load_lds is wave-uniform base + lane*16).
// ---------------------------------------------------------------------------

typedef __attribute__((ext_vector_type(8))) short bf16x8;   // 8 bf16 = 4 VGPRs
typedef __attribute__((ext_vector_type(4))) float f32x4;

#define MFMA_BF16(a, b, c) __builtin_amdgcn_mfma_f32_16x16x32_bf16((a), (b), (c), 0, 0, 0)

__device__ __forceinline__ void load16_lds(const void* g, void* l) {
  __builtin_amdgcn_global_load_lds((const __attribute__((address_space(1))) void*)g,
                                   (__attribute__((address_space(3))) void*)l,
                                   16, 0, 0);
}

__device__ __forceinline__ unsigned short f2bf(float x) {
  union { __hip_bfloat16 b; unsigned short u; } cv;
  cv.b = __float2bfloat16(x);
  return cv.u;
}

// ------------------------------- convert -----------------------------------
__global__ __launch_bounds__(256) void cvt_bf16(const float4* __restrict__ in,
                                                ushort4* __restrict__ out, int n4) {
  int i = blockIdx.x * 256 + threadIdx.x;
  if (i >= n4) return;
  float4 v = in[i];
  ushort4 o;
  o.x = f2bf(v.x); o.y = f2bf(v.y); o.z = f2bf(v.z); o.w = f2bf(v.w);
  out[i] = o;
}

// --------------------------- fused QKV GEMM --------------------------------
// C[2048 x 6144] = A[2048 x 2048] * Bt[6144 x 2048]^T  (both bf16, K-contig)
// Epilogue: +bias, scatter Q->(H,S,D), K->(H,S,D), V->(H,D,S) [transposed]
__global__ __launch_bounds__(256) void gemm_qkv(
    const unsigned short* __restrict__ A, const unsigned short* __restrict__ Bt,
    const float* __restrict__ qb, const float* __restrict__ kb,
    const float* __restrict__ vb,
    unsigned short* __restrict__ Qo, unsigned short* __restrict__ Ko,
    unsigned short* __restrict__ Vt) {
  __shared__ __align__(16) unsigned short sA[128 * 32];
  __shared__ __align__(16) unsigned short sB[128 * 32];
  const int tid = threadIdx.x;
  const int wave = tid >> 6, lane = tid & 63;
  const int quad = lane >> 4, l16 = lane & 15;
  const int wr = wave >> 1, wc = wave & 1;
  const int m0 = blockIdx.y << 7, n0 = blockIdx.x << 7;

  f32x4 acc[4][4] = {};

  for (int k0 = 0; k0 < 2048; k0 += 32) {
    __syncthreads();
    // stage A,B tiles: chunks of 16 rows x 32 (1KB); XOR swizzle blk^(row&3)
    for (int c = wave; c < 8; c += 4) {
      const int rowc = lane >> 2;
      const int blk = (lane & 3) ^ (rowc & 3);
      load16_lds(A + (size_t)(m0 + c * 16 + rowc) * 2048 + k0 + blk * 8, &sA[c * 512]);
      load16_lds(Bt + (size_t)(n0 + c * 16 + rowc) * 2048 + k0 + blk * 8, &sB[c * 512]);
    }
    __syncthreads();
    bf16x8 af[4], bfr[4];
#pragma unroll
    for (int i = 0; i < 4; i++) {
      af[i] = *(const bf16x8*)&sA[(wr * 64 + i * 16 + l16) * 32 + ((quad ^ (l16 & 3)) << 3)];
      bfr[i] = *(const bf16x8*)&sB[(wc * 64 + i * 16 + l16) * 32 + ((quad ^ (l16 & 3)) << 3)];
    }
#pragma unroll
    for (int mi = 0; mi < 4; mi++)
#pragma unroll
      for (int ni = 0; ni < 4; ni++)
        acc[mi][ni] = MFMA_BF16(af[mi], bfr[ni], acc[mi][ni]);
  }

  // epilogue: C/D layout col=lane&15, row=quad*4+reg
#pragma unroll
  for (int mi = 0; mi < 4; mi++) {
    const int row = m0 + wr * 64 + mi * 16 + quad * 4;
#pragma unroll
    for (int ni = 0; ni < 4; ni++) {
      const int col = n0 + wc * 64 + ni * 16 + l16;
#pragma unroll
      for (int r = 0; r < 4; r++) {
        const float v = acc[mi][ni][r];
        const int rr = row + r;
        if (col < 2048) {
          const int hh = col >> 7, d = col & 127;
          Qo[((size_t)hh * 2048 + rr) * 128 + d] = f2bf(v + qb[col]);
        } else if (col < 4096) {
          const int f = col - 2048;
          const int hh = f >> 7, d = f & 127;
          Ko[((size_t)hh * 2048 + rr) * 128 + d] = f2bf(v + kb[f]);
        } else {
          const int f = col - 4096;
          const int hh = f >> 7, d = f & 127;
          Vt[((size_t)hh * 128 + d) * 2048 + rr] = f2bf(v + vb[f]);  // V transposed (H,D,S)
        }
      }
    }
  }
}

// ------------------------------ attention ----------------------------------
// One block = (head, 64-row Q tile). 4 waves x 16 q-rows. Dual accumulators:
// (m2,l2,o2) over all K; fork (m1,l1,o1) at the diagonal tile with causal mask.
__global__ __launch_bounds__(256) void attn_fwd(
    const unsigned short* __restrict__ Q, const unsigned short* __restrict__ K,
    const unsigned short* __restrict__ V,  // V is (H, D, S) transposed
    unsigned short* __restrict__ O,        // (S, H*D) token-major bf16
    const int* __restrict__ wsp) {
  const int h = blockIdx.y;
  const int q0 = blockIdx.x << 6;
  const int tid = threadIdx.x;
  const int wave = tid >> 6, lane = tid & 63;
  const int quad = lane >> 4, l16 = lane & 15;

  __shared__ __align__(16) unsigned short sQ[64 * 128];
  __shared__ __align__(16) unsigned short sK[64 * 128];
  __shared__ __align__(16) unsigned short sV[128 * 64];
  __shared__ __align__(16) unsigned short sP[4][16 * 64];

  const unsigned short* Qh = Q + (size_t)h * 2048 * 128;
  const unsigned short* Kh = K + (size_t)h * 2048 * 128;
  const unsigned short* Vh = V + (size_t)h * 128 * 2048;
  unsigned short* sPw = sP[wave];

  // stage Q tile [64][128], swizzle blk^(row&15)
  for (int c = wave; c < 16; c += 4) {
    const int rowc = lane >> 4;
    const int row = c * 4 + rowc;
    const int blk = (lane & 15) ^ (row & 15);
    load16_lds(Qh + (size_t)(q0 + row) * 128 + blk * 8, &sQ[c * 512]);
  }
  __syncthreads();

  bf16x8 qf[4];
#pragma unroll
  for (int ds = 0; ds < 4; ds++)
    qf[ds] = *(const bf16x8*)&sQ[(wave * 16 + l16) * 128 + (((ds * 4 + quad) ^ l16) << 3)];

  float m1[4], l1[4], m2[4], l2[4];
  f32x4 o1[8], o2[8];
#pragma unroll
  for (int r = 0; r < 4; r++) { m1[r] = m2[r] = -3.0e38f; l1[r] = l2[r] = 0.f; }
#pragma unroll
  for (int j = 0; j < 8; j++) { o1[j] = f32x4{0.f, 0.f, 0.f, 0.f}; o2[j] = f32x4{0.f, 0.f, 0.f, 0.f}; }

  const float scale = 0.088388347648318447f;  // 1/sqrt(128)
  const int diag = q0 >> 6;

  auto update = [&](float (&m)[4], float (&l)[4], f32x4 (&o)[8],
                    const f32x4 (&sc)[4], bool masked, int k0) {
#pragma unroll
    for (int r = 0; r < 4; r++) {
      const int row = q0 + wave * 16 + quad * 4 + r;
      const int qr = quad * 4 + r;
      float s[4];
      float mx = -3.0e38f;
#pragma unroll
      for (int ni = 0; ni < 4; ni++) {
        float v = sc[ni][r] * scale;
        if (masked && (k0 + ni * 16 + l16 > row)) v = -3.0e38f;
        s[ni] = v;
        mx = fmaxf(mx, v);
      }
#pragma unroll
      for (int off = 1; off < 16; off <<= 1) mx = fmaxf(mx, __shfl_xor(mx, off));
      const float mn = fmaxf(m[r], mx);
      const float al = __expf(m[r] - mn);
      float rs = 0.f;
#pragma unroll
      for (int ni = 0; ni < 4; ni++) {
        const float p = __expf(s[ni] - mn);
        rs += p;
        const int pblk = ((ni * 2 + (l16 >> 3)) ^ (qr & 7));
        sPw[qr * 64 + pblk * 8 + (l16 & 7)] = f2bf(p);  // P in A-layout rows, swizzled
      }
#pragma unroll
      for (int off = 1; off < 16; off <<= 1) rs += __shfl_xor(rs, off);
      l[r] = l[r] * al + rs;
      m[r] = mn;
#pragma unroll
      for (int j = 0; j < 8; j++) o[j][r] *= al;
    }
    // PV: o[j] (16q x 16d tile j) += P(16x64) * V(64x16)
#pragma unroll
    for (int ks = 0; ks < 2; ks++) {
      const bf16x8 pf = *(const bf16x8*)&sPw[l16 * 64 + (((ks * 4 + quad) ^ (l16 & 7)) << 3)];
#pragma unroll
      for (int j = 0; j < 8; j++) {
        const bf16x8 vf =
            *(const bf16x8*)&sV[(j * 16 + l16) * 64 + (((ks * 4 + quad) ^ (l16 & 7)) << 3)];
        o[j] = MFMA_BF16(pf, vf, o[j]);
      }
    }
  };

  for (int kt = 0; kt < 32; kt++) {
    const int k0 = kt << 6;
    __syncthreads();
    for (int c = wave; c < 16; c += 4) {
      {  // K tile [64][128]
        const int rowc = lane >> 4;
        const int row = c * 4 + rowc;
        const int blk = (lane & 15) ^ (row & 15);
        load16_lds(Kh + (size_t)(k0 + row) * 128 + blk * 8, &sK[c * 512]);
      }
      {  // V tile [128 d][64 k]
        const int rowc = lane >> 3;
        const int row = c * 8 + rowc;
        const int blk = (lane & 7) ^ (rowc & 7);
        load16_lds(Vh + (size_t)row * 2048 + k0 + blk * 8, &sV[c * 512]);
      }
    }
    __syncthreads();

    // scores: S = Q * K^T (per-wave 16x64)
    f32x4 sc[4];
#pragma unroll
    for (int ni = 0; ni < 4; ni++) sc[ni] = f32x4{0.f, 0.f, 0.f, 0.f};
#pragma unroll
    for (int ds = 0; ds < 4; ds++) {
#pragma unroll
      for (int ni = 0; ni < 4; ni++) {
        const bf16x8 kf =
            *(const bf16x8*)&sK[(ni * 16 + l16) * 128 + (((ds * 4 + quad) ^ l16) << 3)];
        sc[ni] = MFMA_BF16(qf[ds], kf, sc[ni]);
      }
    }

    if (kt == diag) {
#pragma unroll
      for (int r = 0; r < 4; r++) { m1[r] = m2[r]; l1[r] = l2[r]; }
#pragma unroll
      for (int j = 0; j < 8; j++) o1[j] = o2[j];
      update(m1, l1, o1, sc, true, k0);
    }
    update(m2, l2, o2, sc, false, k0);
  }

  // combine: ring = 1x masked + (ws-1)x unmasked, reference epsilon semantics
  const float fws = (float)(wsp[0] - 1);
#pragma unroll
  for (int r = 0; r < 4; r++) {
    const int row = q0 + wave * 16 + quad * 4 + r;
    const float a = __expf(m1[r] - m2[r]);
    const float se = l1[r] * a + fws * l2[r];
    const float c1 = a / (l1[r] + 1e-8f);
    const float c2 = fws / (l2[r] + 1e-8f);
    const float inv = 1.0f / (se + 1e-8f);
#pragma unroll
    for (int j = 0; j < 8; j++) {
      const float ov = (o1[j][r] * c1 + o2[j][r] * c2) * inv;
      O[(size_t)row * 2048 + h * 128 + j * 16 + l16] = f2bf(ov);
    }
  }
}

// ------------------------------ O-proj GEMM --------------------------------
// out[2048 x 2048] fp32 = attn[2048 x 2048]bf16 * ow[2048 x 2048]^T + ob
__global__ __launch_bounds__(256) void gemm_o(
    const unsigned short* __restrict__ A, const unsigned short* __restrict__ Bt,
    const float* __restrict__ ob, float* __restrict__ Cout) {
  __shared__ __align__(16) unsigned short sA[128 * 32];
  __shared__ __align__(16) unsigned short sB[128 * 32];
  const int tid = threadIdx.x;
  const int wave = tid >> 6, lane = tid & 63;
  const int quad = lane >> 4, l16 = lane & 15;
  const int wr = wave >> 1, wc = wave & 1;
  const int m0 = blockIdx.y << 7, n0 = blockIdx.x << 7;

  f32x4 acc[4][4] = {};

  for (int k0 = 0; k0 < 2048; k0 += 32) {
    __syncthreads();
    for (int c = wave; c < 8; c += 4) {
      const int rowc = lane >> 2;
      const int blk = (lane & 3) ^ (rowc & 3);
      load16_lds(A + (size_t)(m0 + c * 16 + rowc) * 2048 + k0 + blk * 8, &sA[c * 512]);
      load16_lds(Bt + (size_t)(n0 + c * 16 + rowc) * 2048 + k0 + blk * 8, &sB[c * 512]);
    }
    __syncthreads();
    bf16x8 af[4], bfr[4];
#pragma unroll
    for (int i = 0; i < 4; i++) {
      af[i] = *(const bf16x8*)&sA[(wr * 64 + i * 16 + l16) * 32 + ((quad ^ (l16 & 3)) << 3)];
      bfr[i] = *(const bf16x8*)&sB[(wc * 64 + i * 16 + l16) * 32 + ((quad ^ (l16 & 3)) << 3)];
    }
#pragma unroll
    for (int mi = 0; mi < 4; mi++)
#pragma unroll
      for (int ni = 0; ni < 4; ni++)
        acc[mi][ni] = MFMA_BF16(af[mi], bfr[ni], acc[mi][ni]);
  }

#pragma unroll
  for (int mi = 0; mi < 4; mi++) {
    const int row = m0 + wr * 64 + mi * 16 + quad * 4;
#pragma unroll
    for (int ni = 0; ni < 4; ni++) {
      const int col = n0 + wc * 64 + ni * 16 + l16;
#pragma unroll
      for (int r = 0; r < 4; r++) {
        Cout[(size_t)(row + r) * 2048 + col] = acc[mi][ni][r] + ob[col];
      }
    }
  }
}

// ------------------------------- launcher ----------------------------------
extern "C" void kernel_launch(void* const* d_in, const int* in_sizes, int n_in,
                              void* d_out, int out_size, void* d_ws, size_t ws_size,
                              hipStream_t stream) {
  (void)in_sizes; (void)n_in; (void)out_size; (void)ws_size;
  const float* hs = (const float*)d_in[0];
  const float* qw = (const float*)d_in[1];
  const float* qb = (const float*)d_in[2];
  const float* kw = (const float*)d_in[3];
  const float* kb = (const float*)d_in[4];
  const float* vw = (const float*)d_in[5];
  const float* vb = (const float*)d_in[6];
  const float* ow = (const float*)d_in[7];
  const float* ob = (const float*)d_in[8];
  const int* wsz = (const int*)d_in[9];

  char* w = (char*)d_ws;
  unsigned short* hsb  = (unsigned short*)(w + 0);          //  8 MB (S,HID) bf16
  unsigned short* wqkv = (unsigned short*)(w + 8388608);    // 24 MB (6144,2048) bf16
  unsigned short* owb  = (unsigned short*)(w + 33554432);   //  8 MB
  unsigned short* Qb_  = (unsigned short*)(w + 41943040);   //  8 MB (H,S,D)
  unsigned short* Kb_  = (unsigned short*)(w + 50331648);   //  8 MB (H,S,D)
  unsigned short* Vtb  = (unsigned short*)(w + 58720256);   //  8 MB (H,D,S)
  unsigned short* atb  = (unsigned short*)(w + 67108864);   //  8 MB (S,H*D)

  const int n4 = 1048576;  // 4194304 / 4
  cvt_bf16<<<4096, 256, 0, stream>>>((const float4*)hs, (ushort4*)hsb, n4);
  cvt_bf16<<<4096, 256, 0, stream>>>((const float4*)qw, (ushort4*)(wqkv), n4);
  cvt_bf16<<<4096, 256, 0, stream>>>((const float4*)kw, (ushort4*)(wqkv + 4194304), n4);
  cvt_bf16<<<4096, 256, 0, stream>>>((const float4*)vw, (ushort4*)(wqkv + 8388608), n4);
  cvt_bf16<<<4096, 256, 0, stream>>>((const float4*)ow, (ushort4*)owb, n4);

  gemm_qkv<<<dim3(48, 16), 256, 0, stream>>>(hsb, wqkv, qb, kb, vb, Qb_, Kb_, Vtb);
  attn_fwd<<<dim3(32, 16), 256, 0, stream>>>(Qb_, Kb_, Vtb, atb, wsz);
  gemm_o<<<dim3(16, 16), 256, 0, stream>>>(atb, owb, ob, (float*)d_out);
}

// Round 2
// 347.839 us; speedup vs baseline: 1.1224x; 1.1224x over previous
//
#include <hip/hip_runtime.h>
#include <hip/hip_bf16.h>
#include <stdint.h>
#include <stddef.h>

// ---------------------------------------------------------------------------
// RingAttentionLayer on MI355X (gfx950)
// R2: GEMMs moved to BK=64 with conflict-free chunk-XOR LDS swizzle
//     (chunk ^ (row&7)); gemm_o retiled 64x128 for 2 blocks/CU; converts
//     fused into one kernel. Attention unchanged from R1 (passing).
// ---------------------------------------------------------------------------

typedef __attribute__((ext_vector_type(8))) short bf16x8;   // 8 bf16 = 4 VGPRs
typedef __attribute__((ext_vector_type(4))) float f32x4;

#define MFMA_BF16(a, b, c) __builtin_amdgcn_mfma_f32_16x16x32_bf16((a), (b), (c), 0, 0, 0)

__device__ __forceinline__ void load16_lds(const void* g, void* l) {
  __builtin_amdgcn_global_load_lds((const __attribute__((address_space(1))) void*)g,
                                   (__attribute__((address_space(3))) void*)l,
                                   16, 0, 0);
}

__device__ __forceinline__ unsigned short f2bf(float x) {
  union { __hip_bfloat16 b; unsigned short u; } cv;
  cv.b = __float2bfloat16(x);
  return cv.u;
}

// ------------------------------- convert -----------------------------------
// All 5 tensors are exactly 4.19M elements (1048576 float4 = 4096 blocks each).
__global__ __launch_bounds__(256) void cvt_all(
    const float4* __restrict__ s0, const float4* __restrict__ s1,
    const float4* __restrict__ s2, const float4* __restrict__ s3,
    const float4* __restrict__ s4,
    ushort4* __restrict__ d0, ushort4* __restrict__ d1,
    ushort4* __restrict__ d2, ushort4* __restrict__ d3,
    ushort4* __restrict__ d4) {
  const int seg = blockIdx.x >> 12;
  const int i = ((blockIdx.x & 4095) << 8) + threadIdx.x;  // 4096*256 == 1048576 exact
  const float4* s = seg == 0 ? s0 : seg == 1 ? s1 : seg == 2 ? s2 : seg == 3 ? s3 : s4;
  ushort4* d = seg == 0 ? d0 : seg == 1 ? d1 : seg == 2 ? d2 : seg == 3 ? d3 : d4;
  float4 v = s[i];
  ushort4 o;
  o.x = f2bf(v.x); o.y = f2bf(v.y); o.z = f2bf(v.z); o.w = f2bf(v.w);
  d[i] = o;
}

// --------------------------- fused QKV GEMM --------------------------------
// C[2048 x 6144] = A[2048 x 2048] * Bt[6144 x 2048]^T  (bf16, K-contig)
// 128x128 tile, BK=64, LDS rows of 128B, chunk-XOR swizzle c^(row&7).
// Epilogue: +bias, scatter Q->(H,S,D), K->(H,S,D), V->(H,D,S) [transposed]
__global__ __launch_bounds__(256) void gemm_qkv(
    const unsigned short* __restrict__ A, const unsigned short* __restrict__ Bt,
    const float* __restrict__ qb, const float* __restrict__ kb,
    const float* __restrict__ vb,
    unsigned short* __restrict__ Qo, unsigned short* __restrict__ Ko,
    unsigned short* __restrict__ Vt) {
  __shared__ __align__(16) unsigned short sA[128 * 64];
  __shared__ __align__(16) unsigned short sB[128 * 64];
  const int tid = threadIdx.x;
  const int wave = tid >> 6, lane = tid & 63;
  const int quad = lane >> 4, l16 = lane & 15;
  const int wr = wave >> 1, wc = wave & 1;
  const int m0 = blockIdx.y << 7, n0 = blockIdx.x << 7;

  f32x4 acc[4][4] = {};

  for (int k0 = 0; k0 < 2048; k0 += 64) {
    __syncthreads();
    // stage: 128 rows x 8 chunks(16B) per tensor = 16 instr; 4 per wave each
#pragma unroll
    for (int t = 0; t < 4; t++) {
      const int i = t * 4 + wave;
      const int idx = i * 64 + lane;
      const int row = idx >> 3;
      const int c = (idx & 7) ^ (row & 7);  // stored chunk (idx&7) holds data chunk c
      load16_lds(A + (size_t)(m0 + row) * 2048 + k0 + c * 8, &sA[i * 512]);
      load16_lds(Bt + (size_t)(n0 + row) * 2048 + k0 + c * 8, &sB[i * 512]);
    }
    __syncthreads();
#pragma unroll
    for (int ks = 0; ks < 2; ks++) {
      bf16x8 af[4], bfr[4];
#pragma unroll
      for (int i = 0; i < 4; i++) {
        const int cs = ((ks * 4 + quad) ^ (l16 & 7)) << 3;
        af[i] = *(const bf16x8*)&sA[(wr * 64 + i * 16 + l16) * 64 + cs];
        bfr[i] = *(const bf16x8*)&sB[(wc * 64 + i * 16 + l16) * 64 + cs];
      }
#pragma unroll
      for (int mi = 0; mi < 4; mi++)
#pragma unroll
        for (int ni = 0; ni < 4; ni++)
          acc[mi][ni] = MFMA_BF16(af[mi], bfr[ni], acc[mi][ni]);
    }
  }

  // epilogue: C/D layout col=lane&15, row=quad*4+reg
#pragma unroll
  for (int mi = 0; mi < 4; mi++) {
    const int row = m0 + wr * 64 + mi * 16 + quad * 4;
#pragma unroll
    for (int ni = 0; ni < 4; ni++) {
      const int col = n0 + wc * 64 + ni * 16 + l16;
#pragma unroll
      for (int r = 0; r < 4; r++) {
        const float v = acc[mi][ni][r];
        const int rr = row + r;
        if (col < 2048) {
          const int hh = col >> 7, d = col & 127;
          Qo[((size_t)hh * 2048 + rr) * 128 + d] = f2bf(v + qb[col]);
        } else if (col < 4096) {
          const int f = col - 2048;
          const int hh = f >> 7, d = f & 127;
          Ko[((size_t)hh * 2048 + rr) * 128 + d] = f2bf(v + kb[f]);
        } else {
          const int f = col - 4096;
          const int hh = f >> 7, d = f & 127;
          Vt[((size_t)hh * 128 + d) * 2048 + rr] = f2bf(v + vb[f]);  // V transposed (H,D,S)
        }
      }
    }
  }
}

// ------------------------------ attention ----------------------------------
// One block = (head, 64-row Q tile). 4 waves x 16 q-rows. Dual accumulators:
// (m2,l2,o2) over all K; fork (m1,l1,o1) at the diagonal tile with causal mask.
__global__ __launch_bounds__(256) void attn_fwd(
    const unsigned short* __restrict__ Q, const unsigned short* __restrict__ K,
    const unsigned short* __restrict__ V,  // V is (H, D, S) transposed
    unsigned short* __restrict__ O,        // (S, H*D) token-major bf16
    const int* __restrict__ wsp) {
  const int h = blockIdx.y;
  const int q0 = blockIdx.x << 6;
  const int tid = threadIdx.x;
  const int wave = tid >> 6, lane = tid & 63;
  const int quad = lane >> 4, l16 = lane & 15;

  __shared__ __align__(16) unsigned short sQ[64 * 128];
  __shared__ __align__(16) unsigned short sK[64 * 128];
  __shared__ __align__(16) unsigned short sV[128 * 64];
  __shared__ __align__(16) unsigned short sP[4][16 * 64];

  const unsigned short* Qh = Q + (size_t)h * 2048 * 128;
  const unsigned short* Kh = K + (size_t)h * 2048 * 128;
  const unsigned short* Vh = V + (size_t)h * 128 * 2048;
  unsigned short* sPw = sP[wave];

  // stage Q tile [64][128], swizzle blk^(row&15)
  for (int c = wave; c < 16; c += 4) {
    const int rowc = lane >> 4;
    const int row = c * 4 + rowc;
    const int blk = (lane & 15) ^ (row & 15);
    load16_lds(Qh + (size_t)(q0 + row) * 128 + blk * 8, &sQ[c * 512]);
  }
  __syncthreads();

  bf16x8 qf[4];
#pragma unroll
  for (int ds = 0; ds < 4; ds++)
    qf[ds] = *(const bf16x8*)&sQ[(wave * 16 + l16) * 128 + (((ds * 4 + quad) ^ l16) << 3)];

  float m1[4], l1[4], m2[4], l2[4];
  f32x4 o1[8], o2[8];
#pragma unroll
  for (int r = 0; r < 4; r++) { m1[r] = m2[r] = -3.0e38f; l1[r] = l2[r] = 0.f; }
#pragma unroll
  for (int j = 0; j < 8; j++) { o1[j] = f32x4{0.f, 0.f, 0.f, 0.f}; o2[j] = f32x4{0.f, 0.f, 0.f, 0.f}; }

  const float scale = 0.088388347648318447f;  // 1/sqrt(128)
  const int diag = q0 >> 6;

  auto update = [&](float (&m)[4], float (&l)[4], f32x4 (&o)[8],
                    const f32x4 (&sc)[4], bool masked, int k0) {
#pragma unroll
    for (int r = 0; r < 4; r++) {
      const int row = q0 + wave * 16 + quad * 4 + r;
      const int qr = quad * 4 + r;
      float s[4];
      float mx = -3.0e38f;
#pragma unroll
      for (int ni = 0; ni < 4; ni++) {
        float v = sc[ni][r] * scale;
        if (masked && (k0 + ni * 16 + l16 > row)) v = -3.0e38f;
        s[ni] = v;
        mx = fmaxf(mx, v);
      }
#pragma unroll
      for (int off = 1; off < 16; off <<= 1) mx = fmaxf(mx, __shfl_xor(mx, off));
      const float mn = fmaxf(m[r], mx);
      const float al = __expf(m[r] - mn);
      float rs = 0.f;
#pragma unroll
      for (int ni = 0; ni < 4; ni++) {
        const float p = __expf(s[ni] - mn);
        rs += p;
        const int pblk = ((ni * 2 + (l16 >> 3)) ^ (qr & 7));
        sPw[qr * 64 + pblk * 8 + (l16 & 7)] = f2bf(p);  // P in A-layout rows, swizzled
      }
#pragma unroll
      for (int off = 1; off < 16; off <<= 1) rs += __shfl_xor(rs, off);
      l[r] = l[r] * al + rs;
      m[r] = mn;
#pragma unroll
      for (int j = 0; j < 8; j++) o[j][r] *= al;
    }
    // PV: o[j] (16q x 16d tile j) += P(16x64) * V(64x16)
#pragma unroll
    for (int ks = 0; ks < 2; ks++) {
      const bf16x8 pf = *(const bf16x8*)&sPw[l16 * 64 + (((ks * 4 + quad) ^ (l16 & 7)) << 3)];
#pragma unroll
      for (int j = 0; j < 8; j++) {
        const bf16x8 vf =
            *(const bf16x8*)&sV[(j * 16 + l16) * 64 + (((ks * 4 + quad) ^ (l16 & 7)) << 3)];
        o[j] = MFMA_BF16(pf, vf, o[j]);
      }
    }
  };

  for (int kt = 0; kt < 32; kt++) {
    const int k0 = kt << 6;
    __syncthreads();
    for (int c = wave; c < 16; c += 4) {
      {  // K tile [64][128]
        const int rowc = lane >> 4;
        const int row = c * 4 + rowc;
        const int blk = (lane & 15) ^ (row & 15);
        load16_lds(Kh + (size_t)(k0 + row) * 128 + blk * 8, &sK[c * 512]);
      }
      {  // V tile [128 d][64 k]
        const int rowc = lane >> 3;
        const int row = c * 8 + rowc;
        const int blk = (lane & 7) ^ (rowc & 7);
        load16_lds(Vh + (size_t)row * 2048 + k0 + blk * 8, &sV[c * 512]);
      }
    }
    __syncthreads();

    // scores: S = Q * K^T (per-wave 16x64)
    f32x4 sc[4];
#pragma unroll
    for (int ni = 0; ni < 4; ni++) sc[ni] = f32x4{0.f, 0.f, 0.f, 0.f};
#pragma unroll
    for (int ds = 0; ds < 4; ds++) {
#pragma unroll
      for (int ni = 0; ni < 4; ni++) {
        const bf16x8 kf =
            *(const bf16x8*)&sK[(ni * 16 + l16) * 128 + (((ds * 4 + quad) ^ l16) << 3)];
        sc[ni] = MFMA_BF16(qf[ds], kf, sc[ni]);
      }
    }

    if (kt == diag) {
#pragma unroll
      for (int r = 0; r < 4; r++) { m1[r] = m2[r]; l1[r] = l2[r]; }
#pragma unroll
      for (int j = 0; j < 8; j++) o1[j] = o2[j];
      update(m1, l1, o1, sc, true, k0);
    }
    update(m2, l2, o2, sc, false, k0);
  }

  // combine: ring = 1x masked + (ws-1)x unmasked, reference epsilon semantics
  const float fws = (float)(wsp[0] - 1);
#pragma unroll
  for (int r = 0; r < 4; r++) {
    const int row = q0 + wave * 16 + quad * 4 + r;
    const float a = __expf(m1[r] - m2[r]);
    const float se = l1[r] * a + fws * l2[r];
    const float c1 = a / (l1[r] + 1e-8f);
    const float c2 = fws / (l2[r] + 1e-8f);
    const float inv = 1.0f / (se + 1e-8f);
#pragma unroll
    for (int j = 0; j < 8; j++) {
      const float ov = (o1[j][r] * c1 + o2[j][r] * c2) * inv;
      O[(size_t)row * 2048 + h * 128 + j * 16 + l16] = f2bf(ov);
    }
  }
}

// ------------------------------ O-proj GEMM --------------------------------
// out[2048 x 2048] fp32 = attn[2048 x 2048]bf16 * ow[2048 x 2048]^T + ob
// 64x128 tile (512 blocks = 2/CU), BK=64, chunk-XOR swizzle.
// Waves 2x2: wave-tile 32 rows x 64 cols.
__global__ __launch_bounds__(256) void gemm_o(
    const unsigned short* __restrict__ A, const unsigned short* __restrict__ Bt,
    const float* __restrict__ ob, float* __restrict__ Cout) {
  __shared__ __align__(16) unsigned short sA[64 * 64];
  __shared__ __align__(16) unsigned short sB[128 * 64];
  const int tid = threadIdx.x;
  const int wave = tid >> 6, lane = tid & 63;
  const int quad = lane >> 4, l16 = lane & 15;
  const int wm = wave >> 1, wn = wave & 1;
  const int m0 = blockIdx.y << 6, n0 = blockIdx.x << 7;

  f32x4 acc[2][4] = {};

  for (int k0 = 0; k0 < 2048; k0 += 64) {
    __syncthreads();
    // A: 64 rows x 8 chunks = 8 instr (2/wave); B: 128 rows = 16 instr (4/wave)
#pragma unroll
    for (int t = 0; t < 2; t++) {
      const int i = t * 4 + wave;
      const int idx = i * 64 + lane;
      const int row = idx >> 3;
      const int c = (idx & 7) ^ (row & 7);
      load16_lds(A + (size_t)(m0 + row) * 2048 + k0 + c * 8, &sA[i * 512]);
    }
#pragma unroll
    for (int t = 0; t < 4; t++) {
      const int i = t * 4 + wave;
      const int idx = i * 64 + lane;
      const int row = idx >> 3;
      const int c = (idx & 7) ^ (row & 7);
      load16_lds(Bt + (size_t)(n0 + row) * 2048 + k0 + c * 8, &sB[i * 512]);
    }
    __syncthreads();
#pragma unroll
    for (int ks = 0; ks < 2; ks++) {
      const int cs = ((ks * 4 + quad) ^ (l16 & 7)) << 3;
      bf16x8 af[2], bfr[4];
#pragma unroll
      for (int i = 0; i < 2; i++)
        af[i] = *(const bf16x8*)&sA[(wm * 32 + i * 16 + l16) * 64 + cs];
#pragma unroll
      for (int i = 0; i < 4; i++)
        bfr[i] = *(const bf16x8*)&sB[(wn * 64 + i * 16 + l16) * 64 + cs];
#pragma unroll
      for (int mi = 0; mi < 2; mi++)
#pragma unroll
        for (int ni = 0; ni < 4; ni++)
          acc[mi][ni] = MFMA_BF16(af[mi], bfr[ni], acc[mi][ni]);
    }
  }

#pragma unroll
  for (int mi = 0; mi < 2; mi++) {
    const int row = m0 + wm * 32 + mi * 16 + quad * 4;
#pragma unroll
    for (int ni = 0; ni < 4; ni++) {
      const int col = n0 + wn * 64 + ni * 16 + l16;
#pragma unroll
      for (int r = 0; r < 4; r++) {
        Cout[(size_t)(row + r) * 2048 + col] = acc[mi][ni][r] + ob[col];
      }
    }
  }
}

// ------------------------------- launcher ----------------------------------
extern "C" void kernel_launch(void* const* d_in, const int* in_sizes, int n_in,
                              void* d_out, int out_size, void* d_ws, size_t ws_size,
                              hipStream_t stream) {
  (void)in_sizes; (void)n_in; (void)out_size; (void)ws_size;
  const float* hs = (const float*)d_in[0];
  const float* qw = (const float*)d_in[1];
  const float* qb = (const float*)d_in[2];
  const float* kw = (const float*)d_in[3];
  const float* kb = (const float*)d_in[4];
  const float* vw = (const float*)d_in[5];
  const float* vb = (const float*)d_in[6];
  const float* ow = (const float*)d_in[7];
  const float* ob = (const float*)d_in[8];
  const int* wsz = (const int*)d_in[9];

  char* w = (char*)d_ws;
  unsigned short* hsb  = (unsigned short*)(w + 0);          //  8 MB (S,HID) bf16
  unsigned short* wqkv = (unsigned short*)(w + 8388608);    // 24 MB (6144,2048) bf16
  unsigned short* owb  = (unsigned short*)(w + 33554432);   //  8 MB
  unsigned short* Qb_  = (unsigned short*)(w + 41943040);   //  8 MB (H,S,D)
  unsigned short* Kb_  = (unsigned short*)(w + 50331648);   //  8 MB (H,S,D)
  unsigned short* Vtb  = (unsigned short*)(w + 58720256);   //  8 MB (H,D,S)
  unsigned short* atb  = (unsigned short*)(w + 67108864);   //  8 MB (S,H*D)

  cvt_all<<<20480, 256, 0, stream>>>(
      (const float4*)hs, (const float4*)qw, (const float4*)kw, (const float4*)vw,
      (const float4*)ow,
      (ushort4*)hsb, (ushort4*)wqkv, (ushort4*)(wqkv + 4194304),
      (ushort4*)(wqkv + 8388608), (ushort4*)owb);

  gemm_qkv<<<dim3(48, 16), 256, 0, stream>>>(hsb, wqkv, qb, kb, vb, Qb_, Kb_, Vtb);
  attn_fwd<<<dim3(32, 16), 256, 0, stream>>>(Qb_, Kb_, Vtb, atb, wsz);
  gemm_o<<<dim3(16, 32), 256, 0, stream>>>(atb, owb, ob, (float*)d_out);
}

// Round 3
// 334.721 us; speedup vs baseline: 1.1664x; 1.0392x over previous
//
#include <hip/hip_runtime.h>
#include <hip/hip_bf16.h>
#include <stdint.h>
#include <stddef.h>

// ---------------------------------------------------------------------------
// RingAttentionLayer on MI355X (gfx950)
// R3: attention rewritten with transposed score MFMA (S^T = K*Q^T) so the
// softmax row reduction is lane-private (15 ops + 2 shfl_xor vs 32 swizzles);
// P written as packed ds_write_b64; exp2-domain softmax with scale*log2e
// folded into the Q epilogue of gemm_qkv. GEMMs unchanged from R2.
// ---------------------------------------------------------------------------

typedef __attribute__((ext_vector_type(8))) short bf16x8;   // 8 bf16 = 4 VGPRs
typedef __attribute__((ext_vector_type(4))) float f32x4;

#define MFMA_BF16(a, b, c) __builtin_amdgcn_mfma_f32_16x16x32_bf16((a), (b), (c), 0, 0, 0)

__device__ __forceinline__ void load16_lds(const void* g, void* l) {
  __builtin_amdgcn_global_load_lds((const __attribute__((address_space(1))) void*)g,
                                   (__attribute__((address_space(3))) void*)l,
                                   16, 0, 0);
}

__device__ __forceinline__ unsigned short f2bf(float x) {
  union { __hip_bfloat16 b; unsigned short u; } cv;
  cv.b = __float2bfloat16(x);
  return cv.u;
}

// ------------------------------- convert -----------------------------------
__global__ __launch_bounds__(256) void cvt_all(
    const float4* __restrict__ s0, const float4* __restrict__ s1,
    const float4* __restrict__ s2, const float4* __restrict__ s3,
    const float4* __restrict__ s4,
    ushort4* __restrict__ d0, ushort4* __restrict__ d1,
    ushort4* __restrict__ d2, ushort4* __restrict__ d3,
    ushort4* __restrict__ d4) {
  const int seg = blockIdx.x >> 12;
  const int i = ((blockIdx.x & 4095) << 8) + threadIdx.x;
  const float4* s = seg == 0 ? s0 : seg == 1 ? s1 : seg == 2 ? s2 : seg == 3 ? s3 : s4;
  ushort4* d = seg == 0 ? d0 : seg == 1 ? d1 : seg == 2 ? d2 : seg == 3 ? d3 : d4;
  float4 v = s[i];
  ushort4 o;
  o.x = f2bf(v.x); o.y = f2bf(v.y); o.z = f2bf(v.z); o.w = f2bf(v.w);
  d[i] = o;
}

// --------------------------- fused QKV GEMM --------------------------------
// C[2048 x 6144] = A[2048 x 2048] * Bt[6144 x 2048]^T  (bf16, K-contig)
// 128x128 tile, BK=64, chunk-XOR swizzle c^(row&7).
// Epilogue: +bias; Q scaled by softmax_scale*log2e; scatter Q->(H,S,D),
// K->(H,S,D), V->(H,D,S) [transposed].
__global__ __launch_bounds__(256) void gemm_qkv(
    const unsigned short* __restrict__ A, const unsigned short* __restrict__ Bt,
    const float* __restrict__ qb, const float* __restrict__ kb,
    const float* __restrict__ vb,
    unsigned short* __restrict__ Qo, unsigned short* __restrict__ Ko,
    unsigned short* __restrict__ Vt) {
  __shared__ __align__(16) unsigned short sA[128 * 64];
  __shared__ __align__(16) unsigned short sB[128 * 64];
  const int tid = threadIdx.x;
  const int wave = tid >> 6, lane = tid & 63;
  const int quad = lane >> 4, l16 = lane & 15;
  const int wr = wave >> 1, wc = wave & 1;
  const int m0 = blockIdx.y << 7, n0 = blockIdx.x << 7;

  f32x4 acc[4][4] = {};

  for (int k0 = 0; k0 < 2048; k0 += 64) {
    __syncthreads();
#pragma unroll
    for (int t = 0; t < 4; t++) {
      const int i = t * 4 + wave;
      const int idx = i * 64 + lane;
      const int row = idx >> 3;
      const int c = (idx & 7) ^ (row & 7);
      load16_lds(A + (size_t)(m0 + row) * 2048 + k0 + c * 8, &sA[i * 512]);
      load16_lds(Bt + (size_t)(n0 + row) * 2048 + k0 + c * 8, &sB[i * 512]);
    }
    __syncthreads();
#pragma unroll
    for (int ks = 0; ks < 2; ks++) {
      bf16x8 af[4], bfr[4];
#pragma unroll
      for (int i = 0; i < 4; i++) {
        const int cs = ((ks * 4 + quad) ^ (l16 & 7)) << 3;
        af[i] = *(const bf16x8*)&sA[(wr * 64 + i * 16 + l16) * 64 + cs];
        bfr[i] = *(const bf16x8*)&sB[(wc * 64 + i * 16 + l16) * 64 + cs];
      }
#pragma unroll
      for (int mi = 0; mi < 4; mi++)
#pragma unroll
        for (int ni = 0; ni < 4; ni++)
          acc[mi][ni] = MFMA_BF16(af[mi], bfr[ni], acc[mi][ni]);
    }
  }

  const float qscale = 0.088388347648318447f * 1.4426950408889634f;  // scale*log2e
#pragma unroll
  for (int mi = 0; mi < 4; mi++) {
    const int row = m0 + wr * 64 + mi * 16 + quad * 4;
#pragma unroll
    for (int ni = 0; ni < 4; ni++) {
      const int col = n0 + wc * 64 + ni * 16 + l16;
#pragma unroll
      for (int r = 0; r < 4; r++) {
        const float v = acc[mi][ni][r];
        const int rr = row + r;
        if (col < 2048) {
          const int hh = col >> 7, d = col & 127;
          Qo[((size_t)hh * 2048 + rr) * 128 + d] = f2bf((v + qb[col]) * qscale);
        } else if (col < 4096) {
          const int f = col - 2048;
          const int hh = f >> 7, d = f & 127;
          Ko[((size_t)hh * 2048 + rr) * 128 + d] = f2bf(v + kb[f]);
        } else {
          const int f = col - 4096;
          const int hh = f >> 7, d = f & 127;
          Vt[((size_t)hh * 128 + d) * 2048 + rr] = f2bf(v + vb[f]);  // (H,D,S)
        }
      }
    }
  }
}

// ------------------------------ attention ----------------------------------
// One block = (head, 64-row Q tile). 4 waves x 16 q-rows. Transposed scores:
// S^T tile = MFMA(K-frag, Q-frag) -> lane (quad,l16) holds scores for column
// q=l16, rows k = ni*16+quad*4+r. Softmax per q is 16 per-lane regs + 2
// shfl_xor across quads. Dual accumulators: (m2,l2,o2) over all K; fork
// (m1,l1,o1) at the diagonal tile with the causal mask.
__global__ __launch_bounds__(256) void attn_fwd(
    const unsigned short* __restrict__ Q, const unsigned short* __restrict__ K,
    const unsigned short* __restrict__ V,  // (H, D, S) transposed
    unsigned short* __restrict__ O,        // (S, H*D) bf16
    const int* __restrict__ wsp) {
  const int h = blockIdx.y;
  const int q0 = blockIdx.x << 6;
  const int tid = threadIdx.x;
  const int wave = tid >> 6, lane = tid & 63;
  const int quad = lane >> 4, l16 = lane & 15;

  __shared__ __align__(16) unsigned short sQ[64 * 128];
  __shared__ __align__(16) unsigned short sK[64 * 128];
  __shared__ __align__(16) unsigned short sV[128 * 64];
  __shared__ __align__(16) unsigned short sP[4][16 * 64];

  const unsigned short* Qh = Q + (size_t)h * 2048 * 128;
  const unsigned short* Kh = K + (size_t)h * 2048 * 128;
  const unsigned short* Vh = V + (size_t)h * 128 * 2048;
  unsigned short* sPw = sP[wave];

  // stage Q tile [64][128], chunk swizzle blk^(row&15)
  for (int c = wave; c < 16; c += 4) {
    const int rowc = lane >> 4;
    const int row = c * 4 + rowc;
    const int blk = (lane & 15) ^ (row & 15);
    load16_lds(Qh + (size_t)(q0 + row) * 128 + blk * 8, &sQ[c * 512]);
  }
  __syncthreads();

  bf16x8 qf[4];
#pragma unroll
  for (int ds = 0; ds < 4; ds++)
    qf[ds] = *(const bf16x8*)&sQ[(wave * 16 + l16) * 128 + (((ds * 4 + quad) ^ l16) << 3)];

  float m1 = -3.0e38f, l1 = 0.f, m2 = -3.0e38f, l2 = 0.f;
  f32x4 o1[8], o2[8];
#pragma unroll
  for (int j = 0; j < 8; j++) { o1[j] = f32x4{0.f, 0.f, 0.f, 0.f}; o2[j] = f32x4{0.f, 0.f, 0.f, 0.f}; }

  const int diag = q0 >> 6;
  const int qg = q0 + wave * 16 + l16;  // this lane's q column (scores domain)

  auto update = [&](float& m, float& l, f32x4 (&o)[8],
                    const f32x4 (&st)[4], bool masked, int k0) {
    // scores already in log2 domain (scale*log2e folded into Q)
    float t[4][4];
    float mx = -3.0e38f;
#pragma unroll
    for (int ni = 0; ni < 4; ni++)
#pragma unroll
      for (int r = 0; r < 4; r++) {
        float v = st[ni][r];
        if (masked && (k0 + ni * 16 + quad * 4 + r > qg)) v = -3.0e38f;
        t[ni][r] = v;
        mx = fmaxf(mx, v);
      }
    mx = fmaxf(mx, __shfl_xor(mx, 16));
    mx = fmaxf(mx, __shfl_xor(mx, 32));
    const float mn = fmaxf(m, mx);
    const float al = exp2f(m - mn);
    float rs = 0.f;
#pragma unroll
    for (int ni = 0; ni < 4; ni++) {
      union { unsigned short u[4]; uint2 v; } pk;
#pragma unroll
      for (int r = 0; r < 4; r++) {
        const float p = exp2f(t[ni][r] - mn);
        rs += p;
        pk.u[r] = f2bf(p);
      }
      // P[q=l16][k], chunk-XOR swizzled: chunk = ni*2+(quad>>1), pos (quad&1)*4
      const int off = l16 * 64 + (((ni * 2 + (quad >> 1)) ^ (l16 & 7)) << 3) + ((quad & 1) << 2);
      *(uint2*)&sPw[off] = pk.v;
    }
    rs += __shfl_xor(rs, 16);
    rs += __shfl_xor(rs, 32);
    l = l * al + rs;
    m = mn;
    // broadcast alpha into the o-accumulator domain (q = quad*4+r)
#pragma unroll
    for (int r = 0; r < 4; r++) {
      const int src = (lane & 48) + ((lane >> 4) << 2) + r;  // same quad, l16=quad*4+r
      const float ab = __shfl(al, src);
#pragma unroll
      for (int j = 0; j < 8; j++) o[j][r] *= ab;
    }
    // PV: o[j] (16q x 16d tile j) += P(16x64) * V(64x16)
#pragma unroll
    for (int ks = 0; ks < 2; ks++) {
      const bf16x8 pf = *(const bf16x8*)&sPw[l16 * 64 + (((ks * 4 + quad) ^ (l16 & 7)) << 3)];
#pragma unroll
      for (int j = 0; j < 8; j++) {
        const bf16x8 vf =
            *(const bf16x8*)&sV[(j * 16 + l16) * 64 + (((ks * 4 + quad) ^ (l16 & 7)) << 3)];
        o[j] = MFMA_BF16(pf, vf, o[j]);
      }
    }
  };

  for (int kt = 0; kt < 32; kt++) {
    const int k0 = kt << 6;
    __syncthreads();
    for (int c = wave; c < 16; c += 4) {
      {  // K tile [64][128]
        const int rowc = lane >> 4;
        const int row = c * 4 + rowc;
        const int blk = (lane & 15) ^ (row & 15);
        load16_lds(Kh + (size_t)(k0 + row) * 128 + blk * 8, &sK[c * 512]);
      }
      {  // V tile [128 d][64 k]
        const int rowc = lane >> 3;
        const int row = c * 8 + rowc;
        const int blk = (lane & 7) ^ (rowc & 7);
        load16_lds(Vh + (size_t)row * 2048 + k0 + blk * 8, &sV[c * 512]);
      }
    }
    __syncthreads();

    // transposed scores: st[ni] = K_tile(ni) * Q^T; C col = q, row = k_local
    f32x4 st[4];
#pragma unroll
    for (int ni = 0; ni < 4; ni++) st[ni] = f32x4{0.f, 0.f, 0.f, 0.f};
#pragma unroll
    for (int ds = 0; ds < 4; ds++) {
#pragma unroll
      for (int ni = 0; ni < 4; ni++) {
        const bf16x8 kf =
            *(const bf16x8*)&sK[(ni * 16 + l16) * 128 + (((ds * 4 + quad) ^ l16) << 3)];
        st[ni] = MFMA_BF16(kf, qf[ds], st[ni]);
      }
    }

    if (kt == diag) {
      m1 = m2; l1 = l2;
#pragma unroll
      for (int j = 0; j < 8; j++) o1[j] = o2[j];
      update(m1, l1, o1, st, true, k0);
    }
    update(m2, l2, o2, st, false, k0);
  }

  // combine: ring = 1x masked + (ws-1)x unmasked (all in log2 domain)
  const float fws = (float)(wsp[0] - 1);
  const float a = exp2f(m1 - m2);
  const float se = l1 * a + fws * l2;
  const float inv = 1.0f / (se + 1e-8f);
  const float f1 = (a / (l1 + 1e-8f)) * inv;
  const float f2 = (fws / (l2 + 1e-8f)) * inv;
#pragma unroll
  for (int r = 0; r < 4; r++) {
    const int src = (lane & 48) + ((lane >> 4) << 2) + r;
    const float f1b = __shfl(f1, src);
    const float f2b = __shfl(f2, src);
    const int row = q0 + wave * 16 + quad * 4 + r;
#pragma unroll
    for (int j = 0; j < 8; j++) {
      const float ov = o1[j][r] * f1b + o2[j][r] * f2b;
      O[(size_t)row * 2048 + h * 128 + j * 16 + l16] = f2bf(ov);
    }
  }
}

// ------------------------------ O-proj GEMM --------------------------------
// out[2048 x 2048] fp32 = attn[2048 x 2048]bf16 * ow[2048 x 2048]^T + ob
__global__ __launch_bounds__(256) void gemm_o(
    const unsigned short* __restrict__ A, const unsigned short* __restrict__ Bt,
    const float* __restrict__ ob, float* __restrict__ Cout) {
  __shared__ __align__(16) unsigned short sA[64 * 64];
  __shared__ __align__(16) unsigned short sB[128 * 64];
  const int tid = threadIdx.x;
  const int wave = tid >> 6, lane = tid & 63;
  const int quad = lane >> 4, l16 = lane & 15;
  const int wm = wave >> 1, wn = wave & 1;
  const int m0 = blockIdx.y << 6, n0 = blockIdx.x << 7;

  f32x4 acc[2][4] = {};

  for (int k0 = 0; k0 < 2048; k0 += 64) {
    __syncthreads();
#pragma unroll
    for (int t = 0; t < 2; t++) {
      const int i = t * 4 + wave;
      const int idx = i * 64 + lane;
      const int row = idx >> 3;
      const int c = (idx & 7) ^ (row & 7);
      load16_lds(A + (size_t)(m0 + row) * 2048 + k0 + c * 8, &sA[i * 512]);
    }
#pragma unroll
    for (int t = 0; t < 4; t++) {
      const int i = t * 4 + wave;
      const int idx = i * 64 + lane;
      const int row = idx >> 3;
      const int c = (idx & 7) ^ (row & 7);
      load16_lds(Bt + (size_t)(n0 + row) * 2048 + k0 + c * 8, &sB[i * 512]);
    }
    __syncthreads();
#pragma unroll
    for (int ks = 0; ks < 2; ks++) {
      const int cs = ((ks * 4 + quad) ^ (l16 & 7)) << 3;
      bf16x8 af[2], bfr[4];
#pragma unroll
      for (int i = 0; i < 2; i++)
        af[i] = *(const bf16x8*)&sA[(wm * 32 + i * 16 + l16) * 64 + cs];
#pragma unroll
      for (int i = 0; i < 4; i++)
        bfr[i] = *(const bf16x8*)&sB[(wn * 64 + i * 16 + l16) * 64 + cs];
#pragma unroll
      for (int mi = 0; mi < 2; mi++)
#pragma unroll
        for (int ni = 0; ni < 4; ni++)
          acc[mi][ni] = MFMA_BF16(af[mi], bfr[ni], acc[mi][ni]);
    }
  }

#pragma unroll
  for (int mi = 0; mi < 2; mi++) {
    const int row = m0 + wm * 32 + mi * 16 + quad * 4;
#pragma unroll
    for (int ni = 0; ni < 4; ni++) {
      const int col = n0 + wn * 64 + ni * 16 + l16;
#pragma unroll
      for (int r = 0; r < 4; r++) {
        Cout[(size_t)(row + r) * 2048 + col] = acc[mi][ni][r] + ob[col];
      }
    }
  }
}

// ------------------------------- launcher ----------------------------------
extern "C" void kernel_launch(void* const* d_in, const int* in_sizes, int n_in,
                              void* d_out, int out_size, void* d_ws, size_t ws_size,
                              hipStream_t stream) {
  (void)in_sizes; (void)n_in; (void)out_size; (void)ws_size;
  const float* hs = (const float*)d_in[0];
  const float* qw = (const float*)d_in[1];
  const float* qb = (const float*)d_in[2];
  const float* kw = (const float*)d_in[3];
  const float* kb = (const float*)d_in[4];
  const float* vw = (const float*)d_in[5];
  const float* vb = (const float*)d_in[6];
  const float* ow = (const float*)d_in[7];
  const float* ob = (const float*)d_in[8];
  const int* wsz = (const int*)d_in[9];

  char* w = (char*)d_ws;
  unsigned short* hsb  = (unsigned short*)(w + 0);          //  8 MB (S,HID) bf16
  unsigned short* wqkv = (unsigned short*)(w + 8388608);    // 24 MB (6144,2048) bf16
  unsigned short* owb  = (unsigned short*)(w + 33554432);   //  8 MB
  unsigned short* Qb_  = (unsigned short*)(w + 41943040);   //  8 MB (H,S,D)
  unsigned short* Kb_  = (unsigned short*)(w + 50331648);   //  8 MB (H,S,D)
  unsigned short* Vtb  = (unsigned short*)(w + 58720256);   //  8 MB (H,D,S)
  unsigned short* atb  = (unsigned short*)(w + 67108864);   //  8 MB (S,H*D)

  cvt_all<<<20480, 256, 0, stream>>>(
      (const float4*)hs, (const float4*)qw, (const float4*)kw, (const float4*)vw,
      (const float4*)ow,
      (ushort4*)hsb, (ushort4*)wqkv, (ushort4*)(wqkv + 4194304),
      (ushort4*)(wqkv + 8388608), (ushort4*)owb);

  gemm_qkv<<<dim3(48, 16), 256, 0, stream>>>(hsb, wqkv, qb, kb, vb, Qb_, Kb_, Vtb);
  attn_fwd<<<dim3(32, 16), 256, 0, stream>>>(Qb_, Kb_, Vtb, atb, wsz);
  gemm_o<<<dim3(16, 32), 256, 0, stream>>>(atb, owb, ob, (float*)d_out);
}